// Round 14
// baseline (83.189 us; speedup 1.0000x reference)
//
#include <hip/hip_runtime.h>

// DkNN p-value: total = sum_k nc[b,k,l]; p = (C - count(cali < total)) / C.
//
// Single fused dispatch, 256 x 1024 (1 block/CU), WAVE-SPECIALIZED prologue:
// separate waves have independent vmcnt streams (in-order retirement is
// per-wave), so hist waves' cali consumes don't wait behind stream prefetch.
//   waves 0..3  (256 thr): LDS-atomic hist of cali (no prefetch issued ->
//                          starts immediately, ~8 us on the LDS pipe)
//   waves 4..15 (768 thr): depth-2 pipelined stream of nc; fold+BUFFER the
//                          first NBUF=6 iterations' sums in registers
//                          (~56 MB streamed during hist -> HBM never idle)
//   barrier; all 1024 threads shfl-scan hist -> float p-value per bin (LDS);
//   barrier; streamers flush 6 buffered lookups (LDS-only) then continue the
//   pipelined consume/refill loop for the remaining ~4.7 iterations.
// R-ledger: R3 fused=64.5 | R5 multi-dispatch=73.5 | R6 naive-special=75.4 |
// R7 grid-barrier=196.8 | R8 16w hidden=60.4 | R9 32w d1=61.2 | R12 pipe=58.7
// | R13 +nt+pval-tbl=57.5. R13 residual = ~9 us HBM-idle during hist (vmcnt
// in-order: cali consume drains prefetch). This kernel = R13 minus that idle.
// Binning: monotone uniform [-8,8), width 2^-9; midpoint error <= peak-bin/2
// ~= 3.9e-4 vs 2e-2 threshold. Integer hist order-independent-> deterministic.
// L templated (=1000) -> div by magic-mul. d_ws unused.

#define NBINS 8192
#define BIN_LO 8.0f
#define BIN_SCALE 512.0f /* NBINS / 16 */
#define BLOCK 1024
#define HISTT 256            /* waves 0..3 */
#define NSTR (BLOCK - HISTT) /* 768 streamers */
#define NBUF 6               /* iterations buffered during hist */

typedef float floatx4 __attribute__((ext_vector_type(4)));

__device__ __forceinline__ int bin_of(float c) {
    float t = (c + BIN_LO) * BIN_SCALE;
    t = fminf(t, (float)(NBINS - 1));
    t = fmaxf(t, 0.0f);
    return (int)t; // monotone in c
}

// In-place: tbl[] = raw int hist on entry, float p-value per bin on exit.
// All 1024 threads; each owns 8 consecutive bins. 2 internal barriers.
__device__ __forceinline__ void scan_pval(int* tbl, int* wsum, int C, float invC) {
    const int t = threadIdx.x;
    const int lane = t & 63;
    const int wid = t >> 6;
    const int base = t * 8;
    float* ftbl = (float*)tbl;
    int h[8];
    int sum = 0;
    #pragma unroll
    for (int i = 0; i < 8; ++i) { h[i] = tbl[base + i]; sum += h[i]; }
    int inc = sum;
    #pragma unroll
    for (int off = 1; off < 64; off <<= 1) {
        int v = __shfl_up(inc, off);
        if (lane >= off) inc += v;
    }
    if (lane == 63) wsum[wid] = inc;
    __syncthreads();
    if (wid == 0) {
        int w = (lane < 16) ? wsum[lane] : 0;
        int winc = w;
        #pragma unroll
        for (int off = 1; off < 16; off <<= 1) {
            int v = __shfl_up(winc, off);
            if (lane >= off) winc += v;
        }
        if (lane < 16) wsum[lane] = winc - w;
    }
    __syncthreads();
    int run = wsum[wid] + (inc - sum);
    #pragma unroll
    for (int i = 0; i < 8; ++i) {
        int midc = (2 * run + h[i]) >> 1;          // (cdf[j]+cdf[j+1])/2
        ftbl[base + i] = (float)(C - midc) * invC; // p-value for this bin
        run += h[i];
    }
}

struct Buf { float4 v[8]; };

__device__ __forceinline__ void load8(Buf& bf, const float* __restrict__ p, int L) {
    #pragma unroll
    for (int k = 0; k < 8; ++k)
        bf.v[k] = *reinterpret_cast<const float4*>(p + k * L);
}

__device__ __forceinline__ void fold8(const Buf& bf, float s[4]) {
    s[0] = ((bf.v[0].x + bf.v[1].x) + (bf.v[2].x + bf.v[3].x)) +
           ((bf.v[4].x + bf.v[5].x) + (bf.v[6].x + bf.v[7].x));
    s[1] = ((bf.v[0].y + bf.v[1].y) + (bf.v[2].y + bf.v[3].y)) +
           ((bf.v[4].y + bf.v[5].y) + (bf.v[6].y + bf.v[7].y));
    s[2] = ((bf.v[0].z + bf.v[1].z) + (bf.v[2].z + bf.v[3].z)) +
           ((bf.v[4].z + bf.v[5].z) + (bf.v[6].z + bf.v[7].z));
    s[3] = ((bf.v[0].w + bf.v[1].w) + (bf.v[2].w + bf.v[3].w)) +
           ((bf.v[4].w + bf.v[5].w) + (bf.v[6].w + bf.v[7].w));
}

__device__ __forceinline__ void lookup_store_nt(const float* ftbl, const float s[4],
                                                float* __restrict__ out, int idx) {
    floatx4 p;
    p.x = ftbl[bin_of(s[0])];
    p.y = ftbl[bin_of(s[1])];
    p.z = ftbl[bin_of(s[2])];
    p.w = ftbl[bin_of(s[3])];
    __builtin_nontemporal_store(p, reinterpret_cast<floatx4*>(out + (idx << 2)));
}

// LT > 0: compile-time L (division -> magic mul). LT == 0: runtime L.
template <int LT>
__global__ __launch_bounds__(BLOCK, 4) void dknn_k8_ws_kernel(
        const float* __restrict__ nc, const float* __restrict__ cali,
        float* __restrict__ out, int n4, int Lrt, int C, float invC) {
    const int L = (LT > 0) ? LT : Lrt;
    const int L7 = 7 * L;
    __shared__ int tbl[NBINS];
    __shared__ int wsum[16];
    const float* ftbl = (const float*)tbl;
    const int t = threadIdx.x;

    const int W = (n4 + gridDim.x - 1) / gridDim.x; // vec4 units per block
    const int beg = blockIdx.x * W;
    const int end = min(n4, beg + W);

    auto rb = [&](int idx) -> const float* {
        int flat = idx << 2;
        int b = flat / L;
        return nc + (size_t)((unsigned)flat + (unsigned)b * (unsigned)L7);
    };

    // zero hist (all threads; 8 ints/thread, stride-1024, conflict-free)
    #pragma unroll
    for (int i = 0; i < NBINS / BLOCK; ++i) tbl[t + i * BLOCK] = 0;
    __syncthreads();

    Buf A, B;
    float sums[NBUF][4];
    const int st = t - HISTT;     // streamer rank (valid when t >= HISTT)
    const int i0 = beg + st;      // streamer's j=0 index

    if (t < HISTT) {
        // HIST role: no prefetch issued by these waves -> cali consumes
        // start immediately (independent per-wave vmcnt).
        const int nvec = C >> 2;
        const float4* cali4 = (const float4*)cali;
        for (int i = t; i < nvec; i += HISTT) {
            float4 v = cali4[i];
            atomicAdd(&tbl[bin_of(v.x)], 1);
            atomicAdd(&tbl[bin_of(v.y)], 1);
            atomicAdd(&tbl[bin_of(v.z)], 1);
            atomicAdd(&tbl[bin_of(v.w)], 1);
        }
        for (int i = (nvec << 2) + t; i < C; i += HISTT)
            atomicAdd(&tbl[bin_of(cali[i])], 1);
    } else {
        // STREAM role: depth-2 pipeline, fold+buffer NBUF iterations' sums.
        load8(A, rb(min(i0, n4 - 1)), L);
        load8(B, rb(min(i0 + NSTR, n4 - 1)), L);
        #pragma unroll
        for (int j = 0; j < NBUF; ++j) {  // static j: sums[] stays in regs
            if (j & 1) {
                fold8(B, sums[j]);
                load8(B, rb(min(i0 + (j + 2) * NSTR, n4 - 1)), L);
            } else {
                fold8(A, sums[j]);
                load8(A, rb(min(i0 + (j + 2) * NSTR, n4 - 1)), L);
            }
        }
    }
    __syncthreads();            // hist complete; streamers: bufs hold j=6,7
    scan_pval(tbl, wsum, C, invC);
    __syncthreads();            // table ready

    if (t >= HISTT) {
        // flush buffered lookups (LDS-only)
        #pragma unroll
        for (int j = 0; j < NBUF; ++j) {
            int idx = i0 + j * NSTR;
            if (idx < end) lookup_store_nt(ftbl, sums[j], out, idx);
        }
        // steady pipelined loop for remaining iterations (A=j6, B=j7 in flight)
        int iA = i0 + NBUF * NSTR;
        int iB = iA + NSTR;
        while (iA < end) {
            float s[4];
            fold8(A, s);
            lookup_store_nt(ftbl, s, out, iA);
            int iN = iB + NSTR;
            load8(A, rb(min(iN, n4 - 1)), L);
            if (iB < end) {
                float r[4];
                fold8(B, r);
                lookup_store_nt(ftbl, r, out, iB);
            }
            int iM = iN + NSTR;
            load8(B, rb(min(iM, n4 - 1)), L);
            iA = iN;
            iB = iM;
        }
    }
}

// Generic fallback (any K, any L): per-block hist, uniform roles.
__global__ __launch_bounds__(BLOCK, 4) void dknn_generic_kernel(
        const float* __restrict__ nc, const float* __restrict__ cali,
        float* __restrict__ out, int BL, int K, int L, int C, float invC) {
    __shared__ int tbl[NBINS];
    __shared__ int wsum[16];
    const float* ftbl = (const float*)tbl;
    const int t = threadIdx.x;
    #pragma unroll
    for (int i = 0; i < NBINS / BLOCK; ++i) tbl[t + i * BLOCK] = 0;
    __syncthreads();
    for (int i = t; i < C; i += BLOCK) atomicAdd(&tbl[bin_of(cali[i])], 1);
    __syncthreads();
    scan_pval(tbl, wsum, C, invC);
    __syncthreads();
    const int stride = gridDim.x * BLOCK;
    for (int i = blockIdx.x * BLOCK + t; i < BL; i += stride) {
        int b = i / L;
        int l = i - b * L;
        const float* base = nc + (size_t)b * (size_t)K * (size_t)L + l;
        float s = 0.f;
        for (int k = 0; k < K; ++k) s += base[(size_t)k * L];
        out[i] = ftbl[bin_of(s)];
    }
}

extern "C" void kernel_launch(void* const* d_in, const int* in_sizes, int n_in,
                              void* d_out, int out_size, void* d_ws, size_t ws_size,
                              hipStream_t stream) {
    const float* nc   = (const float*)d_in[0];
    // d_in[1] = label_sample (unused; only defines L)
    const float* cali = (const float*)d_in[2];

    const int L  = in_sizes[1];
    const int C  = in_sizes[2];
    const int BL = out_size;         // B * L
    const int K  = in_sizes[0] / BL; // 8
    const float invC = 1.0f / (float)C;
    float* out = (float*)d_out;

    if ((L & 3) == 0 && K == 8 && BL >= 4) {
        int n4 = BL >> 2;
        int nblocks = 256; // 1 block/CU
        int needed = (n4 + BLOCK - 1) / BLOCK;
        if (nblocks > needed) nblocks = needed;
        if (L == 1000) {
            dknn_k8_ws_kernel<1000><<<nblocks, BLOCK, 0, stream>>>(
                nc, cali, out, n4, L, C, invC);
        } else {
            dknn_k8_ws_kernel<0><<<nblocks, BLOCK, 0, stream>>>(
                nc, cali, out, n4, L, C, invC);
        }
    } else {
        int nblocks = 512;
        int needed = (BL + BLOCK - 1) / BLOCK;
        if (nblocks > needed) nblocks = needed;
        dknn_generic_kernel<<<nblocks, BLOCK, 0, stream>>>(
            nc, cali, out, BL, K, L, C, invC);
    }
}

// Round 15
// 51.653 us; speedup vs baseline: 1.6105x; 1.6105x over previous
//
#include <hip/hip_runtime.h>

// DkNN p-value: total = sum_k nc[b,k,l]; p = (C - count(cali < total)) / C.
//
// Single fused dispatch, grid 256 x 1024 (1 block/CU), uniform roles (wave
// specialization failed 3x: R6/R7/R14). Structure = R13 (57.5 us) plus
// ISSUE-ORDER-INTERLEAVED prologue:
//   per wave, vmcnt retires in order, so R13's [16 prefetch loads][cali
//   loads+atomics] serialized: first cali consume waited for all prefetch.
//   Now the cali pass is 4 rounds of {issue 7 cali float4 loads -> issue 4
//   prefetch float4 loads -> predicated LDS atomics on the chunk}: each
//   chunk's consume waits only on loads issued before it (one prefetch
//   group ~0.4us, hidden by 16-wave TLP) -> LDS-atomic hist overlaps HBM
//   prefetch delivery instead of following it.
// Then: barrier; shfl block-scan -> float p-value per bin in LDS; barrier;
// steady depth-2 register-pipelined stream (consume/refill) with
// NONTEMPORAL stores (R13 win) and LDS table lookups.
// R-ledger: R3=64.5 | R5 multi-dispatch=73.5 | R6 special=75.4 | R7 grid
// barrier=196.8 | R8=60.4 | R9=61.2 | R12 pipe=58.7 | R13 +nt+pval=57.5 |
// R14 special+spill=83.2.
// Binning: monotone uniform [-8,8), width 2^-9; midpoint error <= peak-bin/2
// ~= 3.9e-4 vs 2e-2 threshold. Integer hist order-independent ->
// deterministic. L templated (=1000) -> div via magic-mul. d_ws unused.

#define NBINS 8192
#define BIN_LO 8.0f
#define BIN_SCALE 512.0f /* NBINS / 16 */
#define BLOCK 1024
#define NROUNDS 4
#define CHUNK 7 /* NROUNDS*CHUNK*BLOCK = 28672 vec4 >= nvec(25000) for C=100k */

typedef float floatx4 __attribute__((ext_vector_type(4)));

__device__ __forceinline__ int bin_of(float c) {
    float t = (c + BIN_LO) * BIN_SCALE;
    t = fminf(t, (float)(NBINS - 1));
    t = fmaxf(t, 0.0f);
    return (int)t; // monotone in c
}

// In-place: tbl[] = raw int hist on entry, float p-value per bin on exit.
// All 1024 threads; each owns 8 consecutive bins. 2 internal barriers.
__device__ __forceinline__ void scan_pval(int* tbl, int* wsum, int C, float invC) {
    const int t = threadIdx.x;
    const int lane = t & 63;
    const int wid = t >> 6;
    const int base = t * 8;
    float* ftbl = (float*)tbl;
    int h[8];
    int sum = 0;
    #pragma unroll
    for (int i = 0; i < 8; ++i) { h[i] = tbl[base + i]; sum += h[i]; }
    int inc = sum;
    #pragma unroll
    for (int off = 1; off < 64; off <<= 1) {
        int v = __shfl_up(inc, off);
        if (lane >= off) inc += v;
    }
    if (lane == 63) wsum[wid] = inc;
    __syncthreads();
    if (wid == 0) {
        int w = (lane < 16) ? wsum[lane] : 0;
        int winc = w;
        #pragma unroll
        for (int off = 1; off < 16; off <<= 1) {
            int v = __shfl_up(winc, off);
            if (lane >= off) winc += v;
        }
        if (lane < 16) wsum[lane] = winc - w;
    }
    __syncthreads();
    int run = wsum[wid] + (inc - sum);
    #pragma unroll
    for (int i = 0; i < 8; ++i) {
        int midc = (2 * run + h[i]) >> 1;          // (cdf[j]+cdf[j+1])/2
        ftbl[base + i] = (float)(C - midc) * invC; // p-value for this bin
        run += h[i];
    }
}

struct Buf { float4 v[8]; };

__device__ __forceinline__ void load8(Buf& bf, const float* __restrict__ p, int L) {
    #pragma unroll
    for (int k = 0; k < 8; ++k)
        bf.v[k] = *reinterpret_cast<const float4*>(p + k * L);
}

__device__ __forceinline__ void fold8(const Buf& bf, float s[4]) {
    s[0] = ((bf.v[0].x + bf.v[1].x) + (bf.v[2].x + bf.v[3].x)) +
           ((bf.v[4].x + bf.v[5].x) + (bf.v[6].x + bf.v[7].x));
    s[1] = ((bf.v[0].y + bf.v[1].y) + (bf.v[2].y + bf.v[3].y)) +
           ((bf.v[4].y + bf.v[5].y) + (bf.v[6].y + bf.v[7].y));
    s[2] = ((bf.v[0].z + bf.v[1].z) + (bf.v[2].z + bf.v[3].z)) +
           ((bf.v[4].z + bf.v[5].z) + (bf.v[6].z + bf.v[7].z));
    s[3] = ((bf.v[0].w + bf.v[1].w) + (bf.v[2].w + bf.v[3].w)) +
           ((bf.v[4].w + bf.v[5].w) + (bf.v[6].w + bf.v[7].w));
}

__device__ __forceinline__ void lookup_store_nt(const float* ftbl, const float s[4],
                                                float* __restrict__ out, int idx) {
    floatx4 p;
    p.x = ftbl[bin_of(s[0])];
    p.y = ftbl[bin_of(s[1])];
    p.z = ftbl[bin_of(s[2])];
    p.w = ftbl[bin_of(s[3])];
    __builtin_nontemporal_store(p, reinterpret_cast<floatx4*>(out + (idx << 2)));
}

// LT > 0: compile-time L (division -> magic mul). LT == 0: runtime L.
template <int LT>
__global__ __launch_bounds__(BLOCK, 4) void dknn_k8_ovl_kernel(
        const float* __restrict__ nc, const float* __restrict__ cali,
        float* __restrict__ out, int n4, int Lrt, int C, float invC) {
    const int L = (LT > 0) ? LT : Lrt;
    const int L7 = 7 * L;
    __shared__ int tbl[NBINS];
    __shared__ int wsum[16];
    const float* ftbl = (const float*)tbl;
    const int t = threadIdx.x;
    const int gid = blockIdx.x * BLOCK + t;
    const int nth = gridDim.x * BLOCK;

    auto rb = [&](int idx) -> const float* {
        int flat = idx << 2;
        int b = flat / L;
        return nc + (size_t)((unsigned)flat + (unsigned)b * (unsigned)L7);
    };

    // zero hist (8 ints/thread, stride-1024, conflict-free)
    #pragma unroll
    for (int i = 0; i < NBINS / BLOCK; ++i) tbl[t + i * BLOCK] = 0;
    __syncthreads();

    // interleaved prologue: cali hist rounds with prefetch issue woven in.
    int iA = gid;
    int iB = gid + nth;
    Buf A, B;
    const float* pa = rb(min(iA, n4 - 1));
    const float* pb = rb(min(iB, n4 - 1));
    const int nvec = C >> 2;
    const float4* cali4 = (const float4*)cali;

    #pragma unroll
    for (int r = 0; r < NROUNDS; ++r) {
        float4 cbuf[CHUNK];
        // issue this round's cali loads (clamped; consume is predicated)
        #pragma unroll
        for (int e = 0; e < CHUNK; ++e) {
            int ci = t + (r * CHUNK + e) * BLOCK;
            cbuf[e] = cali4[min(ci, nvec - 1)];
        }
        // issue 4 prefetch loads: rounds 0,1 -> A; rounds 2,3 -> B
        {
            const float* pp = (r < 2) ? pa : pb;
            Buf& PF = (r < 2) ? A : B;
            #pragma unroll
            for (int k = 0; k < 4; ++k) {
                int kk = (r & 1) * 4 + k;
                PF.v[kk] = *reinterpret_cast<const float4*>(pp + kk * L);
            }
        }
        __builtin_amdgcn_sched_barrier(0); // pin: loads above issue before atomics
        // consume: predicated LDS atomics (waits only on loads issued so far)
        #pragma unroll
        for (int e = 0; e < CHUNK; ++e) {
            int ci = t + (r * CHUNK + e) * BLOCK;
            if (ci < nvec) {
                float4 v = cbuf[e];
                atomicAdd(&tbl[bin_of(v.x)], 1);
                atomicAdd(&tbl[bin_of(v.y)], 1);
                atomicAdd(&tbl[bin_of(v.z)], 1);
                atomicAdd(&tbl[bin_of(v.w)], 1);
            }
        }
        __builtin_amdgcn_sched_barrier(0);
    }
    // general-C catchup (empty for C=100000)
    for (int i = t + NROUNDS * CHUNK * BLOCK; i < nvec; i += BLOCK) {
        float4 v = cali4[i];
        atomicAdd(&tbl[bin_of(v.x)], 1);
        atomicAdd(&tbl[bin_of(v.y)], 1);
        atomicAdd(&tbl[bin_of(v.z)], 1);
        atomicAdd(&tbl[bin_of(v.w)], 1);
    }
    for (int i = (nvec << 2) + t; i < C; i += BLOCK)
        atomicAdd(&tbl[bin_of(cali[i])], 1);

    // table: hist -> float p-value per bin (in place)
    __syncthreads();
    scan_pval(tbl, wsum, C, invC);
    __syncthreads();

    // steady pipelined stream: consume A, refill A(i+2); consume B, refill B(i+3)
    while (iA < n4) {
        float s[4];
        fold8(A, s);
        lookup_store_nt(ftbl, s, out, iA);
        int iN = iB + nth;
        load8(A, rb(min(iN, n4 - 1)), L);
        if (iB < n4) {
            float r[4];
            fold8(B, r);
            lookup_store_nt(ftbl, r, out, iB);
        }
        int iM = iN + nth;
        load8(B, rb(min(iM, n4 - 1)), L);
        iA = iN;
        iB = iM;
    }
}

// Generic fallback (any K, any L): per-block hist, uniform roles.
__global__ __launch_bounds__(BLOCK, 4) void dknn_generic_kernel(
        const float* __restrict__ nc, const float* __restrict__ cali,
        float* __restrict__ out, int BL, int K, int L, int C, float invC) {
    __shared__ int tbl[NBINS];
    __shared__ int wsum[16];
    const float* ftbl = (const float*)tbl;
    const int t = threadIdx.x;
    #pragma unroll
    for (int i = 0; i < NBINS / BLOCK; ++i) tbl[t + i * BLOCK] = 0;
    __syncthreads();
    for (int i = t; i < C; i += BLOCK) atomicAdd(&tbl[bin_of(cali[i])], 1);
    __syncthreads();
    scan_pval(tbl, wsum, C, invC);
    __syncthreads();
    const int stride = gridDim.x * BLOCK;
    for (int i = blockIdx.x * BLOCK + t; i < BL; i += stride) {
        int b = i / L;
        int l = i - b * L;
        const float* base = nc + (size_t)b * (size_t)K * (size_t)L + l;
        float s = 0.f;
        for (int k = 0; k < K; ++k) s += base[(size_t)k * L];
        out[i] = ftbl[bin_of(s)];
    }
}

extern "C" void kernel_launch(void* const* d_in, const int* in_sizes, int n_in,
                              void* d_out, int out_size, void* d_ws, size_t ws_size,
                              hipStream_t stream) {
    const float* nc   = (const float*)d_in[0];
    // d_in[1] = label_sample (unused; only defines L)
    const float* cali = (const float*)d_in[2];

    const int L  = in_sizes[1];
    const int C  = in_sizes[2];
    const int BL = out_size;         // B * L
    const int K  = in_sizes[0] / BL; // 8
    const float invC = 1.0f / (float)C;
    float* out = (float*)d_out;

    if ((L & 3) == 0 && K == 8 && BL >= 4 && C >= 4) {
        int n4 = BL >> 2;
        int nblocks = 256; // 1 block/CU
        int needed = (n4 + BLOCK - 1) / BLOCK;
        if (nblocks > needed) nblocks = needed;
        if (L == 1000) {
            dknn_k8_ovl_kernel<1000><<<nblocks, BLOCK, 0, stream>>>(
                nc, cali, out, n4, L, C, invC);
        } else {
            dknn_k8_ovl_kernel<0><<<nblocks, BLOCK, 0, stream>>>(
                nc, cali, out, n4, L, C, invC);
        }
    } else {
        int nblocks = 512;
        int needed = (BL + BLOCK - 1) / BLOCK;
        if (nblocks > needed) nblocks = needed;
        dknn_generic_kernel<<<nblocks, BLOCK, 0, stream>>>(
            nc, cali, out, BL, K, L, C, invC);
    }
}